// Round 7
// baseline (400.027 us; speedup 1.0000x reference)
//
#include <hip/hip_runtime.h>
#include <hip/hip_bf16.h>

#define SS   50     // sequence length
#define DD   300    // embedding dim
#define NH   15     // heads
#define HD   20     // per-head dim
#define QDIM 200    // additive attention dim

// ws (bf16 elements): 5 proj [304][320] + Wa [208][320]
#define WSEG  97280
#define WAOFF 486400
#define WTOT  552960

typedef __attribute__((ext_vector_type(8)))  short bf8t;
typedef __attribute__((ext_vector_type(4)))  float f4t;
typedef __attribute__((ext_vector_type(16))) float f16t;

__device__ __forceinline__ unsigned short f2bf(float x){
  unsigned u = __float_as_uint(x);
  return (unsigned short)((u + 0x7fffu + ((u >> 16) & 1u)) >> 16);
}
__device__ __forceinline__ unsigned packbf(float a, float b){
  return (unsigned)f2bf(a) | ((unsigned)f2bf(b) << 16);
}
__device__ __forceinline__ f16t zero16(){
  f16t v;
  #pragma unroll
  for (int i = 0; i < 16; ++i) v[i] = 0.f;
  return v;
}

// ---------------- weight converter: f32 [300][N] -> bf16 [Npad][320] (B^T, zero-padded)
__global__ __launch_bounds__(256) void conv_weights(
    const float* __restrict__ Wq, const float* __restrict__ Wk,
    const float* __restrict__ Wv, const float* __restrict__ Wqp,
    const float* __restrict__ Wkp, const float* __restrict__ Wa,
    short* __restrict__ ws)
{
  int idx = blockIdx.x*256 + threadIdx.x;
  if (idx >= WTOT) return;
  float v = 0.f;
  if (idx < WAOFF){
    int seg = idx / WSEG, r = idx - seg*WSEG;
    int n = r / 320, k = r - n*320;
    const float* W = (seg==0)?Wq:(seg==1)?Wk:(seg==2)?Wv:(seg==3)?Wqp:Wkp;
    if (n < DD && k < DD) v = W[k*DD + n];
  } else {
    int r = idx - WAOFF;
    int n = r / 320, k = r - n*320;
    if (n < QDIM && k < DD) v = Wa[k*QDIM + n];
  }
  ws[idx] = (short)f2bf(v);
}

// ---------------- pooling GEMM helper: acc += A(LDS,stride656) @ B(ws), 10 k-steps
template<int NT, int NCTM>
__device__ __forceinline__ void gemm10(const unsigned char* sm, unsigned abase,
                                       const short* __restrict__ wt,
                                       int lane, int w, f4t (&acc)[NT][4])
{
  const int lm = lane & 15, lg = lane >> 4;
  #pragma unroll
  for (int step = 0; step < 10; ++step){
    bf8t a[4];
    #pragma unroll
    for (int rt = 0; rt < 4; ++rt)
      a[rt] = *(const bf8t*)(sm + abase + (unsigned)(rt*16 + lm)*656u + (unsigned)(step*32 + lg*8)*2u);
    #pragma unroll
    for (int t = 0; t < NT; ++t){
      int ct = w + t*8; if (ct > NCTM) ct = NCTM;
      bf8t bb = *(const bf8t*)(wt + (size_t)(ct*16 + lm)*320 + step*32 + lg*8);
      #pragma unroll
      for (int rt = 0; rt < 4; ++rt)
        acc[t][rt] = __builtin_amdgcn_mfma_f32_16x16x32_bf16(a[rt], bb, acc[t][rt], 0, 0, 0);
    }
  }
}

// ============================ K1: projections ================================
// LDS: uv [50][328]bf16 stride656 @0; ue @32800; (overread pad to 64 rows); ids @74784
// 75KB LDS -> 2 blocks/CU = 4 waves/SIMD, so declare (512,4) for a 128-VGPR budget;
// B-fragments preloaded to registers so the 10-20 global loads pipeline.
#define K1_UV  0
#define K1_UE  32800
#define K1_IDS 74784
#define K1_SM  74992

__global__ __launch_bounds__(512, 4) void k1_proj(
    const int*   __restrict__ ids, const float* __restrict__ uv,
    const float* __restrict__ emb,
    const float* __restrict__ bq, const float* __restrict__ bk,
    const float* __restrict__ bv, const float* __restrict__ bqp,
    const float* __restrict__ bkp,
    const short* __restrict__ wsb,
    short* __restrict__ qg, short* __restrict__ kg, short* __restrict__ vg)
{
  __shared__ __align__(16) unsigned char sm[K1_SM];
  const int tid  = threadIdx.x;
  const int b    = blockIdx.x;
  const int w    = tid >> 6;
  const int lane = tid & 63;
  const int lm   = lane & 15, lg = lane >> 4;

  const short* wqT  = wsb;
  const short* wkT  = wsb + WSEG;
  const short* wvT  = wsb + 2*WSEG;
  const short* wqpT = wsb + 3*WSEG;
  const short* wkpT = wsb + 4*WSEG;

  if (tid < SS) *(int*)(sm + K1_IDS + tid*4) = ids[(size_t)b*SS + tid];
  {
    const float* srcv = uv + (size_t)b*SS*DD;
    for (int i = tid; i < SS*75; i += 512){
      int s = i/75, j4 = i - s*75;
      float4 v = *(const float4*)(srcv + s*DD + j4*4);
      *(unsigned*)(sm + K1_UV + (unsigned)s*656 + (unsigned)j4*8)     = packbf(v.x, v.y);
      *(unsigned*)(sm + K1_UV + (unsigned)s*656 + (unsigned)j4*8 + 4) = packbf(v.z, v.w);
    }
    for (int i = tid; i < SS*28; i += 512){   // uv+ue k-pads (cols 300..327)
      int s = i/28, j = i - s*28;
      unsigned off = (j < 14) ? (K1_UV + (unsigned)s*656 + 600u + (unsigned)j*4)
                              : (K1_UE + (unsigned)s*656 + 600u + (unsigned)(j-14)*4);
      *(unsigned*)(sm + off) = 0;
    }
  }
  __syncthreads();
  for (int i = tid; i < SS*75; i += 512){     // gather ue
    int s = i/75, j4 = i - s*75;
    int id = *(const int*)(sm + K1_IDS + s*4);
    float4 v = *(const float4*)(emb + (size_t)id*DD + j4*4);
    *(unsigned*)(sm + K1_UE + (unsigned)s*656 + (unsigned)j4*8)     = packbf(v.x, v.y);
    *(unsigned*)(sm + K1_UE + (unsigned)s*656 + (unsigned)j4*8 + 4) = packbf(v.z, v.w);
  }
  __syncthreads();

  // zero 48-dim pads (cols head*48 + 40..47) of qg/kg rows of this b
  for (int i = tid; i < SS*15*4; i += 512){
    int row = i / 60, r2 = i - row*60;
    int head = r2 >> 2, j = r2 & 3;
    size_t base = ((size_t)b*SS + row)*720 + head*48 + 40 + j*2;
    *(unsigned*)(qg + base) = 0u;
    *(unsigned*)(kg + base) = 0u;
  }

  // 152 task-units: g in {Qc,Qp,V,K}, 19 col-tiles, 2 row-halves
  for (int u = w; u < 152; u += 8){
    const int g   = u / 38;
    const int rem = u - g*38;
    const int c   = rem >> 1, rh = rem & 1;
    const int col  = c*16 + lm;
    const int colc = (col < DD) ? col : DD-1;
    const bool valid = (col < DD);
    const int head = colc / HD;
    const int dd   = colc - head*HD;
    const unsigned abase = (g == 1) ? (unsigned)K1_UE : (unsigned)K1_UV;
    const short* wt = (g==0) ? wqT : (g==1) ? wqpT : (g==2) ? wvT : wkT;
    const short* wb = wt + (size_t)col*320 + lg*8;

    if (g == 3){
      // K: Kc = uv@Wk + bk ; Ksum = Kc + ue@Wkp + bkp. Preload BOTH GEMMs'
      // fragments (20 x 16B = 80 VGPR) so all global loads pipeline.
      const short* wb2 = wkpT + (size_t)col*320 + lg*8;
      bf8t wr1[10], wr2[10];
      #pragma unroll
      for (int st = 0; st < 10; ++st) wr1[st] = *(const bf8t*)(wb + st*32);
      #pragma unroll
      for (int st = 0; st < 10; ++st) wr2[st] = *(const bf8t*)(wb2 + st*32);
      f4t a0 = {0.f,0.f,0.f,0.f}, a1 = {0.f,0.f,0.f,0.f};
      #pragma unroll
      for (int st = 0; st < 10; ++st){
        bf8t x0 = *(const bf8t*)(sm + K1_UV + (unsigned)(rh*32 + lm)*656u + (unsigned)(st*32 + lg*8)*2u);
        bf8t x1 = *(const bf8t*)(sm + K1_UV + (unsigned)(rh*32 + 16 + lm)*656u + (unsigned)(st*32 + lg*8)*2u);
        a0 = __builtin_amdgcn_mfma_f32_16x16x32_bf16(x0, wr1[st], a0, 0, 0, 0);
        a1 = __builtin_amdgcn_mfma_f32_16x16x32_bf16(x1, wr1[st], a1, 0, 0, 0);
      }
      float bkc = bk[colc];
      if (valid){
        size_t koff = (size_t)head*48 + 20 + dd;   // Kc slot
        #pragma unroll
        for (int i = 0; i < 4; ++i){
          int r0 = rh*32 + lg*4 + i;
          if (r0 < SS) kg[((size_t)b*SS + r0)*720 + koff] = (short)f2bf(a0[i]+bkc);
          int r1 = rh*32 + 16 + lg*4 + i;
          if (r1 < SS) kg[((size_t)b*SS + r1)*720 + koff] = (short)f2bf(a1[i]+bkc);
        }
      }
      #pragma unroll
      for (int st = 0; st < 10; ++st){
        bf8t x0 = *(const bf8t*)(sm + K1_UE + (unsigned)(rh*32 + lm)*656u + (unsigned)(st*32 + lg*8)*2u);
        bf8t x1 = *(const bf8t*)(sm + K1_UE + (unsigned)(rh*32 + 16 + lm)*656u + (unsigned)(st*32 + lg*8)*2u);
        a0 = __builtin_amdgcn_mfma_f32_16x16x32_bf16(x0, wr2[st], a0, 0, 0, 0);
        a1 = __builtin_amdgcn_mfma_f32_16x16x32_bf16(x1, wr2[st], a1, 0, 0, 0);
      }
      if (valid){
        float bsum = bkc + bkp[colc];
        size_t koff = (size_t)head*48 + dd;        // Ksum slot
        #pragma unroll
        for (int i = 0; i < 4; ++i){
          int r0 = rh*32 + lg*4 + i;
          if (r0 < SS) kg[((size_t)b*SS + r0)*720 + koff] = (short)f2bf(a0[i]+bsum);
          int r1 = rh*32 + 16 + lg*4 + i;
          if (r1 < SS) kg[((size_t)b*SS + r1)*720 + koff] = (short)f2bf(a1[i]+bsum);
        }
      }
    } else {
      bf8t wr[10];
      #pragma unroll
      for (int st = 0; st < 10; ++st) wr[st] = *(const bf8t*)(wb + st*32);
      f4t a0 = {0.f,0.f,0.f,0.f}, a1 = {0.f,0.f,0.f,0.f};
      #pragma unroll
      for (int st = 0; st < 10; ++st){
        bf8t x0 = *(const bf8t*)(sm + abase + (unsigned)(rh*32 + lm)*656u + (unsigned)(st*32 + lg*8)*2u);
        bf8t x1 = *(const bf8t*)(sm + abase + (unsigned)(rh*32 + 16 + lm)*656u + (unsigned)(st*32 + lg*8)*2u);
        a0 = __builtin_amdgcn_mfma_f32_16x16x32_bf16(x0, wr[st], a0, 0, 0, 0);
        a1 = __builtin_amdgcn_mfma_f32_16x16x32_bf16(x1, wr[st], a1, 0, 0, 0);
      }
      if (g == 2){                       // V -> natural layout [b][row][300]
        if (valid){
          float bias = bv[colc];
          #pragma unroll
          for (int i = 0; i < 4; ++i){
            int r0 = rh*32 + lg*4 + i;
            if (r0 < SS) vg[((size_t)b*SS + r0)*300 + col] = (short)f2bf(a0[i]+bias);
            int r1 = rh*32 + 16 + lg*4 + i;
            if (r1 < SS) vg[((size_t)b*SS + r1)*300 + col] = (short)f2bf(a1[i]+bias);
          }
        }
      } else {                           // Qc/Qp -> [b][row][head*48 + (0|20) + dd]
        if (valid){
          float bias = (g==0) ? bq[colc] : bqp[colc];
          size_t qoff = (size_t)head*48 + dd + (g==1 ? 20 : 0);
          #pragma unroll
          for (int i = 0; i < 4; ++i){
            int r0 = rh*32 + lg*4 + i;
            if (r0 < SS) qg[((size_t)b*SS + r0)*720 + qoff] = (short)f2bf(a0[i]+bias);
            int r1 = rh*32 + 16 + lg*4 + i;
            if (r1 < SS) qg[((size_t)b*SS + r1)*720 + qoff] = (short)f2bf(a1[i]+bias);
          }
        }
      }
    }
  }
}

// ============================ K2: attention ==================================
// block = (b, head-group hg of <=4 heads). LDS:
//   Q [50][192]bf16 stride400 @0 ; K @20000 ; VT [92][64keys]bf16 stride144 @40000
//   P overlays Q/K: per-wave [32][64] stride144 @ w*4608
#define A_Q   0
#define A_K   20000
#define A_VT  40000
#define A_PBLK 4608
#define A_SM  53248

__global__ __launch_bounds__(512) void k2_attn(
    const short* __restrict__ qg, const short* __restrict__ kg,
    const short* __restrict__ vg, short* __restrict__ cg)
{
  __shared__ __align__(16) unsigned char sm[A_SM];
  const int tid  = threadIdx.x;
  const int bid  = blockIdx.x;
  const int b    = bid >> 2;
  const int hg   = bid & 3;
  const int nheads = (hg < 3) ? 4 : 3;
  const int w    = tid >> 6;
  const int lane = tid & 63;
  const int l31  = lane & 31, hi = lane >> 5;

  // zero VT (keys>=50 must be 0; rows 80..91 finite)
  for (int i = tid; i < 828; i += 512)
    *(float4*)(sm + A_VT + (unsigned)i*16) = make_float4(0.f,0.f,0.f,0.f);
  __syncthreads();
  // stage Q,K rows (24 float4 per row)
  for (int i = tid; i < 2400; i += 512){
    int arr = (i < 1200) ? 0 : 1;
    int j = i - arr*1200;
    int row = j/24, c = j - row*24;
    const short* src = (arr ? kg : qg) + ((size_t)b*SS + row)*720 + hg*192 + c*8;
    float4 v = *(const float4*)src;
    *(float4*)(sm + (arr ? A_K : A_Q) + (unsigned)row*400 + (unsigned)c*16) = v;
  }
  // stage VT (transpose): read u32 (2 dims) per (row,d2)
  for (int i = tid; i < 2000; i += 512){
    int row = i/40, d2 = i - row*40;
    unsigned v = *(const unsigned*)(vg + ((size_t)b*SS + row)*300 + hg*80 + d2*2);
    *(unsigned short*)(sm + A_VT + (unsigned)(d2*2)*144   + (unsigned)row*2) = (unsigned short)(v & 0xffffu);
    *(unsigned short*)(sm + A_VT + (unsigned)(d2*2+1)*144 + (unsigned)row*2) = (unsigned short)(v >> 16);
  }
  __syncthreads();

  const float rscale = 0.1290994449f;  // 1/sqrt(3*DK)
  const int ahl = w >> 1, rt = w & 1;
  const bool act = (ahl < nheads);
  f16t s0, s1;
  if (act){
    s0 = zero16(); s1 = zero16();
    unsigned aoff = A_Q + (unsigned)(rt*32 + l31)*400 + (unsigned)ahl*96 + (unsigned)hi*16;
    unsigned koff = A_K + (unsigned)l31*400 + (unsigned)ahl*96 + (unsigned)hi*16;
    #pragma unroll
    for (int ks = 0; ks < 3; ++ks){
      bf8t a  = *(const bf8t*)(sm + aoff + ks*32);
      bf8t b0 = *(const bf8t*)(sm + koff + ks*32);
      bf8t b1 = *(const bf8t*)(sm + koff + 32u*400 + ks*32);
      s0 = __builtin_amdgcn_mfma_f32_32x32x16_bf16(a, b0, s0, 0, 0, 0);
      s1 = __builtin_amdgcn_mfma_f32_32x32x16_bf16(a, b1, s1, 0, 0, 0);
    }
  }
  __syncthreads();   // Q/K reads done -> P may overwrite
  if (act){
    const bool m1 = (l31 >= 18);   // key 32+l31 >= 50
    unsigned pb = (unsigned)w*A_PBLK;
    float rinv[16];
    #pragma unroll
    for (int r = 0; r < 16; ++r){
      int lrow = (r&3) + 8*(r>>2) + 4*hi;
      float v0 = s0[r]*rscale;
      float v1 = m1 ? -INFINITY : s1[r]*rscale;
      float mx = fmaxf(v0, v1);
      #pragma unroll
      for (int off = 1; off <= 16; off <<= 1) mx = fmaxf(mx, __shfl_xor(mx, off));
      float e0 = __expf(v0 - mx);
      float e1 = m1 ? 0.f : __expf(v1 - mx);
      float sum = e0 + e1;
      #pragma unroll
      for (int off = 1; off <= 16; off <<= 1) sum += __shfl_xor(sum, off);
      rinv[r] = 1.0f/sum;
      *(unsigned short*)(sm + pb + (unsigned)lrow*144 + (unsigned)l31*2)      = f2bf(e0);
      *(unsigned short*)(sm + pb + (unsigned)lrow*144 + 64 + (unsigned)l31*2) = f2bf(e1);
    }
    f16t c = zero16();
    unsigned pa  = pb + (unsigned)l31*144 + (unsigned)hi*16;
    unsigned vb2 = A_VT + (unsigned)(ahl*HD + l31)*144 + (unsigned)hi*16;
    #pragma unroll
    for (int ks = 0; ks < 4; ++ks){
      bf8t a = *(const bf8t*)(sm + pa + ks*32);
      bf8t v = *(const bf8t*)(sm + vb2 + ks*32);
      c = __builtin_amdgcn_mfma_f32_32x32x16_bf16(a, v, c, 0, 0, 0);
    }
    if (l31 < HD){
      int h = hg*4 + ahl;
      #pragma unroll
      for (int r = 0; r < 16; ++r){
        int q = rt*32 + (r&3) + 8*(r>>2) + 4*hi;
        if (q < SS)
          cg[((size_t)b*SS + q)*300 + h*HD + l31] = (short)f2bf(c[r]*rinv[r]);
      }
    }
  }
}

// ============================ K3: pooling ====================================
// LDS: ctx bf16 [64 rows][328] stride656 @0 (rows>=50 garbage, discarded);
//      lg2d f32 [50][8] @41984; a f32[64] @44032
#define B_CTX 0
#define B_LG  41984
#define B_A2  44032
#define B_SM  44288

__global__ __launch_bounds__(512) void k3_pool(
    const short* __restrict__ cg, const short* __restrict__ wsb,
    const float* __restrict__ ba, const float* __restrict__ qa,
    float* __restrict__ out)
{
  __shared__ __align__(16) unsigned char sm[B_SM];
  const int tid  = threadIdx.x;
  const int b    = blockIdx.x;
  const int w    = tid >> 6;
  const int lane = tid & 63;
  const int lm   = lane & 15, lg = lane >> 4;
  const short* waT = wsb + WAOFF;

  // stage ctx: uint2 = 4 bf16 per iter; 75 iters/row * 4 = 300 elements/row
  for (int i = tid; i < SS*75; i += 512){
    int row = i/75, c = i - row*75;
    uint2 v = *(const uint2*)(cg + ((size_t)b*SS + row)*300 + c*4);
    *(uint2*)(sm + B_CTX + (unsigned)row*656 + (unsigned)c*8) = v;
  }
  for (int i = tid; i < SS*14; i += 512)
    *(unsigned*)(sm + B_CTX + (unsigned)(i/14)*656 + 600u + (unsigned)(i%14)*4) = 0;
  __syncthreads();

  {
    f4t accp[2][4];
    #pragma unroll
    for (int t = 0; t < 2; ++t)
      #pragma unroll
      for (int r = 0; r < 4; ++r) accp[t][r] = (f4t){0.f,0.f,0.f,0.f};
    gemm10<2,12>(sm, B_CTX, waT, lane, w, accp);
    float part[4][4];
    #pragma unroll
    for (int rt2 = 0; rt2 < 4; ++rt2)
      #pragma unroll
      for (int i = 0; i < 4; ++i) part[rt2][i] = 0.f;
    #pragma unroll
    for (int t = 0; t < 2; ++t){
      int ct = w + t*8; if (ct > 12) ct = 12;
      bool valid = (t == 0) || (w < 5);
      int col = ct*16 + lm;
      float bav = (col < QDIM) ? ba[col] : 0.f;
      float qav = (valid && col < QDIM) ? qa[col] : 0.f;
      #pragma unroll
      for (int rt2 = 0; rt2 < 4; ++rt2)
        #pragma unroll
        for (int i = 0; i < 4; ++i)
          part[rt2][i] += tanhf(accp[t][rt2][i] + bav) * qav;
    }
    #pragma unroll
    for (int off = 1; off <= 8; off <<= 1)
      #pragma unroll
      for (int rt2 = 0; rt2 < 4; ++rt2)
        #pragma unroll
        for (int i = 0; i < 4; ++i)
          part[rt2][i] += __shfl_xor(part[rt2][i], off);
    if (lm == 0){
      #pragma unroll
      for (int rt2 = 0; rt2 < 4; ++rt2)
        #pragma unroll
        for (int i = 0; i < 4; ++i){
          int row = rt2*16 + lg*4 + i;
          if (row < SS) *(float*)(sm + B_LG + (unsigned)(row*8 + w)*4) = part[rt2][i];
        }
    }
  }
  __syncthreads();
  if (w == 0){
    const int sl = lane < SS ? lane : SS - 1;
    const bool rowok = lane < SS;
    float lgv = -INFINITY;
    if (rowok){
      float s = 0.f;
      #pragma unroll
      for (int j = 0; j < 8; ++j) s += *(const float*)(sm + B_LG + (unsigned)(sl*8 + j)*4);
      lgv = s;
    }
    float m = lgv;
    #pragma unroll
    for (int off = 32; off; off >>= 1) m = fmaxf(m, __shfl_xor(m, off));
    float e = rowok ? __expf(lgv - m) : 0.f;
    float ssum = e;
    #pragma unroll
    for (int off = 32; off; off >>= 1) ssum += __shfl_xor(ssum, off);
    *(float*)(sm + B_A2 + lane*4) = e / ssum;
  }
  __syncthreads();
  if (tid < DD){
    float accv = 0.f;
    for (int s = 0; s < SS; ++s){
      float av = *(const float*)(sm + B_A2 + (unsigned)s*4);
      unsigned short cv = *(const unsigned short*)(sm + B_CTX + (unsigned)s*656 + (unsigned)tid*2);
      accv = fmaf(av, __uint_as_float((unsigned)cv << 16), accv);
    }
    out[(size_t)b*DD + tid] = accv;
  }
}

// ===================== fallback: round-4 fused kernel ========================
#define OFF_UV  0
#define OFF_UE  32800
#define QKSTR   400
#define OFF_Q   65600
#define OFF_K   85600
#define OFF_P   65600
#define PBLK    4608
#define PSTR    144
#define VTSTR   144
#define OFF_VT  105600
#define OFF_CTX 117120
#define OFF_LG  159104
#define OFF_A2  161152
#define OFF_IDS 161408
#define SM_TOTAL 161616

__global__ __launch_bounds__(512) void user_enc_kernel(
    const int*   __restrict__ ids, const float* __restrict__ uv,
    const float* __restrict__ emb,
    const float* __restrict__ bq, const float* __restrict__ bk,
    const float* __restrict__ bv, const float* __restrict__ bqp,
    const float* __restrict__ bkp,
    const float* __restrict__ ba, const float* __restrict__ qa,
    const short* __restrict__ wsb, float* __restrict__ out)
{
  __shared__ __align__(16) unsigned char sm[SM_TOTAL];
  const int tid  = threadIdx.x;
  const int b    = blockIdx.x;
  const int w    = tid >> 6;
  const int lane = tid & 63;
  const int lm   = lane & 15, lg = lane >> 4;
  const int l31  = lane & 31, hi = lane >> 5;

  const short* wqT  = wsb;
  const short* wkT  = wsb + WSEG;
  const short* wvT  = wsb + 2*WSEG;
  const short* wqpT = wsb + 3*WSEG;
  const short* wkpT = wsb + 4*WSEG;
  const short* waT  = wsb + WAOFF;

  if (tid < SS) *(int*)(sm + OFF_IDS + tid*4) = ids[(size_t)b*SS + tid];
  {
    const float* srcv = uv + (size_t)b*SS*DD;
    for (int i = tid; i < SS*75; i += 512){
      int s = i/75, j4 = i - s*75;
      float4 v = *(const float4*)(srcv + s*DD + j4*4);
      *(unsigned*)(sm + OFF_UV + (unsigned)s*656 + (unsigned)j4*8)     = packbf(v.x, v.y);
      *(unsigned*)(sm + OFF_UV + (unsigned)s*656 + (unsigned)j4*8 + 4) = packbf(v.z, v.w);
    }
    for (int i = tid; i < SS*28; i += 512){
      int s = i/28, j = i - s*28;
      unsigned off = (j < 14) ? (OFF_UV + (unsigned)s*656 + 600u + (unsigned)j*4)
                              : (OFF_UE + (unsigned)s*656 + 600u + (unsigned)(j-14)*4);
      *(unsigned*)(sm + off) = 0;
    }
    for (int i = tid; i < SS*14; i += 512)
      *(unsigned*)(sm + OFF_CTX + (unsigned)(i/14)*656 + 600u + (unsigned)(i%14)*4) = 0;
    for (int i = tid; i < 720; i += 512)
      *(float4*)(sm + OFF_VT + (unsigned)i*16) = make_float4(0.f,0.f,0.f,0.f);
  }
  __syncthreads();
  for (int i = tid; i < SS*75; i += 512){
    int s = i/75, j4 = i - s*75;
    int id = *(const int*)(sm + OFF_IDS + s*4);
    float4 v = *(const float4*)(emb + (size_t)id*DD + j4*4);
    *(unsigned*)(sm + OFF_UE + (unsigned)s*656 + (unsigned)j4*8)     = packbf(v.x, v.y);
    *(unsigned*)(sm + OFF_UE + (unsigned)s*656 + (unsigned)j4*8 + 4) = packbf(v.z, v.w);
  }

  const float rscale = 0.1290994449f;
  #pragma unroll 1
  for (int nb4 = 0; nb4 < 4; ++nb4){
    const int nheads = (nb4 < 3) ? 4 : 3;
    const int NCT    = (nb4 < 3) ? 5 : 4;
    __syncthreads();
    for (int i = tid; i < SS*4; i += 512){
      int r = i >> 2, hl0 = i & 3;
      *(float4*)(sm + OFF_Q + (unsigned)r*QKSTR + (unsigned)hl0*96 + 80) = make_float4(0.f,0.f,0.f,0.f);
      *(float4*)(sm + OFF_K + (unsigned)r*QKSTR + (unsigned)hl0*96 + 80) = make_float4(0.f,0.f,0.f,0.f);
    }
    for (int ht = w; ht < 8*NCT; ht += 8){
      const int g   = (ht >= 6*NCT) ? 3 : (ht >= 4*NCT) ? 2 : (ht >= 2*NCT) ? 1 : 0;
      const int rem = ht - g*2*NCT;
      const int c   = rem >> 1, rh = rem & 1;
      const int col = nb4*80 + c*16 + lm;
      const int colc = (col < DD) ? col : DD-1;
      const int head = col / HD;
      const int dd   = col - head*HD;
      const int hl   = head - nb4*4;
      const bool valid = (hl < nheads) && (col < DD);
      const unsigned abase = (g == 1) ? (unsigned)OFF_UE : (unsigned)OFF_UV;
      const short* wt = (g==0) ? wqT : (g==1) ? wqpT : (g==2) ? wvT : wkT;
      const short* wb = wt + (size_t)col*320 + lg*8;
      f4t a0 = {0.f,0.f,0.f,0.f}, a1 = {0.f,0.f,0.f,0.f};
      #pragma unroll
      for (int st = 0; st < 10; ++st){
        bf8t bb = *(const bf8t*)(wb + st*32);
        bf8t x0 = *(const bf8t*)(sm + abase + (unsigned)(rh*32 + lm)*656u + (unsigned)(st*32 + lg*8)*2u);
        bf8t x1 = *(const bf8t*)(sm + abase + (unsigned)(rh*32 + 16 + lm)*656u + (unsigned)(st*32 + lg*8)*2u);
        a0 = __builtin_amdgcn_mfma_f32_16x16x32_bf16(x0, bb, a0, 0, 0, 0);
        a1 = __builtin_amdgcn_mfma_f32_16x16x32_bf16(x1, bb, a1, 0, 0, 0);
      }
      if (g == 2){
        if (valid){
          float bias = bv[colc];
          unsigned vb = OFF_VT + (unsigned)(hl*HD + dd)*VTSTR;
          int r0 = rh*32 + lg*4;
          if (r0 < SS){
            *(unsigned*)(sm + vb + (unsigned)r0*2) = packbf(a0[0]+bias, a0[1]+bias);
            if (r0+2 < SS) *(unsigned*)(sm + vb + (unsigned)r0*2 + 4) = packbf(a0[2]+bias, a0[3]+bias);
          }
          int r1 = rh*32 + 16 + lg*4;
          if (r1 < SS){
            *(unsigned*)(sm + vb + (unsigned)r1*2) = packbf(a1[0]+bias, a1[1]+bias);
            if (r1+2 < SS) *(unsigned*)(sm + vb + (unsigned)r1*2 + 4) = packbf(a1[2]+bias, a1[3]+bias);
          }
        }
      } else if (g != 3){
        if (valid){
          float bias = (g==0) ? bq[colc] : bqp[colc];
          unsigned qb = OFF_Q + (unsigned)hl*96 + (unsigned)dd*2 + (g==1 ? 40u : 0u);
          #pragma unroll
          for (int i = 0; i < 4; ++i){
            int r0 = rh*32 + lg*4 + i;
            if (r0 < SS) *(unsigned short*)(sm + qb + (unsigned)r0*QKSTR) = f2bf(a0[i]+bias);
            int r1 = rh*32 + 16 + lg*4 + i;
            if (r1 < SS) *(unsigned short*)(sm + qb + (unsigned)r1*QKSTR) = f2bf(a1[i]+bias);
          }
        }
      } else {
        float bkc = bk[colc];
        if (valid){
          unsigned kb = OFF_K + (unsigned)hl*96 + (unsigned)dd*2 + 40u;
          #pragma unroll
          for (int i = 0; i < 4; ++i){
            int r0 = rh*32 + lg*4 + i;
            if (r0 < SS) *(unsigned short*)(sm + kb + (unsigned)r0*QKSTR) = f2bf(a0[i]+bkc);
            int r1 = rh*32 + 16 + lg*4 + i;
            if (r1 < SS) *(unsigned short*)(sm + kb + (unsigned)r1*QKSTR) = f2bf(a1[i]+bkc);
          }
        }
        const short* wb2 = wkpT + (size_t)col*320 + lg*8;
        #pragma unroll
        for (int st = 0; st < 10; ++st){
          bf8t bb = *(const bf8t*)(wb2 + st*32);
          bf8t x0 = *(const bf8t*)(sm + OFF_UE + (unsigned)(rh*32 + lm)*656u + (unsigned)(st*32 + lg*8)*2u);
          bf8t x1 = *(const bf8t*)(sm + OFF_UE + (unsigned)(rh*32 + 16 + lm)*656u + (unsigned)(st*32 + lg*8)*2u);
          a0 = __builtin_amdgcn_mfma_f32_16x16x32_bf16(x0, bb, a0, 0, 0, 0);
          a1 = __builtin_amdgcn_mfma_f32_16x16x32_bf16(x1, bb, a1, 0, 0, 0);
        }
        if (valid){
          float bsum = bkc + bkp[colc];
          unsigned kb = OFF_K + (unsigned)hl*96 + (unsigned)dd*2;
          #pragma unroll
          for (int i = 0; i < 4; ++i){
            int r0 = rh*32 + lg*4 + i;
            if (r0 < SS) *(unsigned short*)(sm + kb + (unsigned)r0*QKSTR) = f2bf(a0[i]+bsum);
            int r1 = rh*32 + 16 + lg*4 + i;
            if (r1 < SS) *(unsigned short*)(sm + kb + (unsigned)r1*QKSTR) = f2bf(a1[i]+bsum);
          }
        }
      }
    }
    __syncthreads();
    const int ahl = w >> 1, rt = w & 1;
    const bool act = (ahl < nheads);
    f16t s0, s1;
    if (act){
      s0 = zero16(); s1 = zero16();
      unsigned aoff = OFF_Q + (unsigned)(rt*32 + l31)*QKSTR + (unsigned)ahl*96 + (unsigned)hi*16;
      unsigned koff = OFF_K + (unsigned)l31*QKSTR + (unsigned)ahl*96 + (unsigned)hi*16;
      #pragma unroll
      for (int ks = 0; ks < 3; ++ks){
        bf8t a  = *(const bf8t*)(sm + aoff + ks*32);
        bf8t b0 = *(const bf8t*)(sm + koff + ks*32);
        bf8t b1 = *(const bf8t*)(sm + koff + 32u*QKSTR + ks*32);
        s0 = __builtin_amdgcn_mfma_f32_32x32x16_bf16(a, b0, s0, 0, 0, 0);
        s1 = __builtin_amdgcn_mfma_f32_32x32x16_bf16(a, b1, s1, 0, 0, 0);
      }
    }
    __syncthreads();
    if (act){
      const bool m1 = (l31 >= 18);
      unsigned pb = OFF_P + (unsigned)w*PBLK;
      float rinv[16];
      #pragma unroll
      for (int r = 0; r < 16; ++r){
        int lrow = (r&3) + 8*(r>>2) + 4*hi;
        float v0 = s0[r]*rscale;
        float v1 = m1 ? -INFINITY : s1[r]*rscale;
        float mx = fmaxf(v0, v1);
        #pragma unroll
        for (int off = 1; off <= 16; off <<= 1) mx = fmaxf(mx, __shfl_xor(mx, off));
        float e0 = __expf(v0 - mx);
        float e1 = m1 ? 0.f : __expf(v1 - mx);
        float sum = e0 + e1;
        #pragma unroll
        for (int off = 1; off <= 16; off <<= 1) sum += __shfl_xor(sum, off);
        rinv[r] = 1.0f/sum;
        *(unsigned short*)(sm + pb + (unsigned)lrow*PSTR + (unsigned)l31*2)      = f2bf(e0);
        *(unsigned short*)(sm + pb + (unsigned)lrow*PSTR + 64 + (unsigned)l31*2) = f2bf(e1);
      }
      f16t c = zero16();
      unsigned pa  = pb + (unsigned)l31*PSTR + (unsigned)hi*16;
      unsigned vb2 = OFF_VT + (unsigned)(ahl*HD + l31)*VTSTR + (unsigned)hi*16;
      #pragma unroll
      for (int ks = 0; ks < 4; ++ks){
        bf8t a = *(const bf8t*)(sm + pa + ks*32);
        bf8t v = *(const bf8t*)(sm + vb2 + ks*32);
        c = __builtin_amdgcn_mfma_f32_32x32x16_bf16(a, v, c, 0, 0, 0);
      }
      if (l31 < HD){
        int h = nb4*4 + ahl;
        #pragma unroll
        for (int r = 0; r < 16; ++r){
          int q = rt*32 + (r&3) + 8*(r>>2) + 4*hi;
          if (q < SS)
            *(unsigned short*)(sm + OFF_CTX + (unsigned)q*656 + (unsigned)(h*HD + l31)*2) =
                f2bf(c[r]*rinv[r]);
        }
      }
    }
  }
  __syncthreads();

  {
    f4t accp[2][4];
    #pragma unroll
    for (int t = 0; t < 2; ++t)
      #pragma unroll
      for (int r = 0; r < 4; ++r) accp[t][r] = (f4t){0.f,0.f,0.f,0.f};
    gemm10<2,12>(sm, OFF_CTX, waT, lane, w, accp);
    float part[4][4];
    #pragma unroll
    for (int rt2 = 0; rt2 < 4; ++rt2)
      #pragma unroll
      for (int i = 0; i < 4; ++i) part[rt2][i] = 0.f;
    #pragma unroll
    for (int t = 0; t < 2; ++t){
      int ct = w + t*8; if (ct > 12) ct = 12;
      bool valid = (t == 0) || (w < 5);
      int col = ct*16 + lm;
      float bav = (col < QDIM) ? ba[col] : 0.f;
      float qav = (valid && col < QDIM) ? qa[col] : 0.f;
      #pragma unroll
      for (int rt2 = 0; rt2 < 4; ++rt2)
        #pragma unroll
        for (int i = 0; i < 4; ++i)
          part[rt2][i] += tanhf(accp[t][rt2][i] + bav) * qav;
    }
    #pragma unroll
    for (int off = 1; off <= 8; off <<= 1)
      #pragma unroll
      for (int rt2 = 0; rt2 < 4; ++rt2)
        #pragma unroll
        for (int i = 0; i < 4; ++i)
          part[rt2][i] += __shfl_xor(part[rt2][i], off);
    if (lm == 0){
      #pragma unroll
      for (int rt2 = 0; rt2 < 4; ++rt2)
        #pragma unroll
        for (int i = 0; i < 4; ++i){
          int row = rt2*16 + lg*4 + i;
          if (row < SS) *(float*)(sm + OFF_LG + (unsigned)(row*8 + w)*4) = part[rt2][i];
        }
    }
  }
  __syncthreads();
  if (w == 0){
    const int sl = lane < SS ? lane : SS - 1;
    const bool rowok = lane < SS;
    float lgv = -INFINITY;
    if (rowok){
      float s = 0.f;
      #pragma unroll
      for (int j = 0; j < 8; ++j) s += *(const float*)(sm + OFF_LG + (unsigned)(sl*8 + j)*4);
      lgv = s;
    }
    float m = lgv;
    #pragma unroll
    for (int off = 32; off; off >>= 1) m = fmaxf(m, __shfl_xor(m, off));
    float e = rowok ? __expf(lgv - m) : 0.f;
    float ssum = e;
    #pragma unroll
    for (int off = 32; off; off >>= 1) ssum += __shfl_xor(ssum, off);
    *(float*)(sm + OFF_A2 + lane*4) = e / ssum;
  }
  __syncthreads();
  if (tid < DD){
    float accv = 0.f;
    for (int s = 0; s < SS; ++s){
      float av = *(const float*)(sm + OFF_A2 + (unsigned)s*4);
      unsigned short cv = *(const unsigned short*)(sm + OFF_CTX + (unsigned)s*656 + (unsigned)tid*2);
      accv = fmaf(av, __uint_as_float((unsigned)cv << 16), accv);
    }
    out[(size_t)b*DD + tid] = accv;
  }
}

extern "C" void kernel_launch(void* const* d_in, const int* in_sizes, int n_in,
                              void* d_out, int out_size, void* d_ws, size_t ws_size,
                              hipStream_t stream){
  (void)n_in; (void)out_size;
  const int*   ids = (const int*)  d_in[0];
  const float* uvp = (const float*)d_in[1];
  const float* emb = (const float*)d_in[2];
  const float* Wq  = (const float*)d_in[3];
  const float* bq  = (const float*)d_in[4];
  const float* Wk  = (const float*)d_in[5];
  const float* bk  = (const float*)d_in[6];
  const float* Wv  = (const float*)d_in[7];
  const float* bv  = (const float*)d_in[8];
  const float* Wqp = (const float*)d_in[9];
  const float* bqp = (const float*)d_in[10];
  const float* Wkp = (const float*)d_in[11];
  const float* bkp = (const float*)d_in[12];
  const float* Wa  = (const float*)d_in[13];
  const float* ba  = (const float*)d_in[14];
  const float* qa  = (const float*)d_in[15];
  short* wsb = (short*)d_ws;

  const int nb = in_sizes[0] / SS;   // 1024
  const size_t wbytes = (size_t)WTOT * 2;
  const size_t qelems = (size_t)nb * SS * 720;
  const size_t velems = (size_t)nb * SS * 300;
  const size_t need   = wbytes + 2*qelems*2 + 2*velems*2;

  conv_weights<<<(WTOT + 255)/256, 256, 0, stream>>>(Wq, Wk, Wv, Wqp, Wkp, Wa, wsb);

  if (ws_size >= need){
    short* qg = (short*)((char*)d_ws + wbytes);
    short* kg = qg + qelems;
    short* vg = kg + qelems;
    short* cg = vg + velems;
    k1_proj<<<nb, 512, 0, stream>>>(ids, uvp, emb, bq, bk, bv, bqp, bkp,
                                    (const short*)wsb, qg, kg, vg);
    k2_attn<<<nb*4, 512, 0, stream>>>((const short*)qg, (const short*)kg,
                                      (const short*)vg, cg);
    k3_pool<<<nb, 512, 0, stream>>>((const short*)cg, (const short*)wsb,
                                    ba, qa, (float*)d_out);
  } else {
    user_enc_kernel<<<nb, 512, 0, stream>>>(ids, uvp, emb,
                                            bq, bk, bv, bqp, bkp, ba, qa,
                                            (const short*)wsb, (float*)d_out);
  }
}